// Round 7
// baseline (70.483 us; speedup 1.0000x reference)
//
#include <hip/hip_runtime.h>
#include <cstdint>
#include <cstddef>

// ---- problem constants ----
static constexpr int BATCH = 32;
static constexpr int CIN   = 3;
static constexpr int HIN   = 224, WIN = 224;
static constexpr int COUT  = 64;
static constexpr int HOUT  = 56, WOUT = 56;
static constexpr int NPIX  = HOUT * WOUT;     // 3136 = 49*64
static constexpr int NEXP  = 8;
static constexpr int PH    = 227;             // padded rows: 3 zero rows on top
static constexpr int PW    = 232;             // 3 left pad + 224 + 5 right pad
static constexpr int KROWS = 21;              // ci*7 + kh
static constexpr int KPAD2 = 192;             // 24 rows * 8 slots
static constexpr int NKS   = 6;               // K-steps of 32
static constexpr float LN_EPS_F = 1e-6f;

// k_pre role partition
static constexpr int CONV_SLICES = 16;
static constexpr int ROWS_PER_SLICE = 15;     // 16*15 = 240 >= 227
static constexpr int N_CONV = BATCH * CIN * CONV_SLICES;          // 1536
static constexpr int N_GATE = BATCH * CIN;                        // 96
static constexpr int N_REPACK = (9 * COUT * KPAD2 + 255) / 256;   // 432

typedef __bf16 bf16x8 __attribute__((ext_vector_type(8)));
typedef float  f32x4  __attribute__((ext_vector_type(4)));

// ---- device-global scratch ----
__device__ __align__(16) ushort g_xbf[BATCH * CIN * PH * PW];  // padded bf16 x (~10.1 MB)
__device__ __align__(16) ushort g_pw2[9 * COUT * KPAD2];       // bf16 weights, k' layout
__device__ float g_gateinp[BATCH * CIN];

__device__ __forceinline__ ushort f2bf(float f) {
  uint u = __float_as_uint(f);
  uint r = (u + 0x7FFFu + ((u >> 16) & 1u)) >> 16;             // RNE
  return (ushort)r;
}

// ---------------- kernel 1: fused convert (0..1535) / gate_mean (1536..1631) /
//                             repack (1632..2063) ----------------
__global__ __launch_bounds__(256) void k_pre(const float* __restrict__ x,
                                             const float* __restrict__ eW,
                                             const float* __restrict__ sW) {
  const int bid = blockIdx.x;
  if (bid < N_CONV) {
    // ---- pad + f32->bf16 convert: one 15-row slice of one (b,ci) plane ----
    const int plane = bid / CONV_SLICES;
    const int slice = bid - plane * CONV_SLICES;
    const float* __restrict__ src = x + (size_t)plane * (HIN * WIN);
    uint* __restrict__ dst = reinterpret_cast<uint*>(g_xbf + (size_t)plane * (PH * PW));
    const int i0 = slice * (ROWS_PER_SLICE * (PW / 2));
    const int iN = PH * (PW / 2);
    const int i1 = (i0 + ROWS_PER_SLICE * (PW / 2) < iN) ? i0 + ROWS_PER_SLICE * (PW / 2) : iN;
    for (int i = i0 + (int)threadIdx.x; i < i1; i += 256) {
      const int r = i / (PW / 2);
      const int j = i - r * (PW / 2);
      uint o = 0u;
      if (r >= 3) {                 // rows 0..2 are zero padding
        const int ih = r - 3;
        const int c0 = 2 * j - 3;   // input col for padded col 2j
        const int c1 = 2 * j - 2;   // input col for padded col 2j+1
        const float f0 = ((unsigned)c0 < (unsigned)WIN) ? src[ih * WIN + c0] : 0.f;
        const float f1 = ((unsigned)c1 < (unsigned)WIN) ? src[ih * WIN + c1] : 0.f;
        o = (uint)f2bf(f0) | ((uint)f2bf(f1) << 16);
      }
      dst[i] = o;
    }
  } else if (bid < N_CONV + N_GATE) {
    // ---- gate_inp = mean_{H,W}(x), f32-exact, coalesced float4 ----
    const int plane = bid - N_CONV;
    const float4* p4 = reinterpret_cast<const float4*>(x + (size_t)plane * (HIN * WIN));
    float s = 0.f;
    for (int i = threadIdx.x; i < (HIN * WIN) / 4; i += 256) {
      const float4 v = p4[i];
      s += v.x + v.y + v.z + v.w;
    }
    __shared__ float red[256];
    red[threadIdx.x] = s;
    __syncthreads();
    for (int off = 128; off > 0; off >>= 1) {
      if ((int)threadIdx.x < off) red[threadIdx.x] += red[threadIdx.x + off];
      __syncthreads();
    }
    if (threadIdx.x == 0) g_gateinp[plane] = red[0] * (1.f / (float)(HIN * WIN));
  } else {
    // ---- repack weights -> bf16 [9][64][192], k' = (ci*7+kh)*8 + kw ----
    const int idx = (bid - N_CONV - N_GATE) * 256 + threadIdx.x;
    if (idx >= 9 * COUT * KPAD2) return;
    const int k2  = idx % KPAD2;
    const int coe = idx / KPAD2;    // e*64 + co
    const int co  = coe & 63;
    const int e   = coe >> 6;
    const int kw  = k2 & 7;
    const int row = k2 >> 3;
    float v = 0.f;
    if (kw < 7 && row < KROWS) {
      const int k = row * 7 + kw;
      v = (e < 8) ? eW[(size_t)coe * 147 + k] : sW[(size_t)co * 147 + k];
    }
    g_pw2[idx] = f2bf(v);
  }
}

// ---------------- kernel 2: MFMA conv + LN + gated combine (+gating +loss) ----------
// Block: 1 image x 64 pixels, 4 waves; wave w owns co slice [16w,16w+16).
// All B-fragment loads issued as ONE burst before the gating VALU work; A-loads
// as a second burst; MFMAs run with all operands in registers.
__global__ __launch_bounds__(256) void k_main(
    const float* __restrict__ w_gate,
    const float* __restrict__ eB, const float* __restrict__ sB,
    const float* __restrict__ elnw, const float* __restrict__ elnb,
    const float* __restrict__ slnw, const float* __restrict__ slnb,
    float* __restrict__ out, float* __restrict__ loss_out) {
  __shared__ float2 Sstats[4 * 3 * 4 * 16];   // [wave][expert][cb][col] (6 KB)

  const int tid  = threadIdx.x;
  const int lane = tid & 63;
  const int w    = tid >> 6;
  const int b    = blockIdx.x / (NPIX / 64);
  const int t    = blockIdx.x % (NPIX / 64);
  const int t64  = t * 64;

  // ---- per-lane address precompute (before everything: B loads first!) ----
  const int m    = lane >> 4;        // k-chunk index (0..3)
  const int colA = lane & 15;        // A: co row / B: pixel col
  const ushort* __restrict__ bimg = g_xbf + (size_t)b * (CIN * PH * PW);

  int pbase[4];
  #pragma unroll
  for (int cb = 0; cb < 4; ++cb) {
    const int pg = t64 + cb * 16 + colA;
    const int oh = pg / WOUT;
    const int ow = pg - oh * WOUT;
    pbase[cb] = (oh * 4) * PW + ow * 4;      // padded coords: ih' = oh*4+kh, col = ow*4+kw
  }
  int offs[NKS];
  #pragma unroll
  for (int ks = 0; ks < NKS; ++ks) {
    int row = ks * 4 + m;
    row = row > 20 ? 20 : row;               // rows 21..23: weights are zero, clamp addr
    const int ci = row >= 14 ? 2 : (row >= 7 ? 1 : 0);
    const int kh = row - ci * 7;
    offs[ks] = (ci * PH + kh) * PW;
  }

  // ---- burst 1: ALL B-fragment loads (independent of gating) ----
  uint2 Blo[4][NKS], Bhi[4][NKS];
  #pragma unroll
  for (int cb = 0; cb < 4; ++cb) {
    #pragma unroll
    for (int ks = 0; ks < NKS; ++ks) {
      const ushort* bp = bimg + pbase[cb] + offs[ks];
      Blo[cb][ks] = *reinterpret_cast<const uint2*>(bp);       // 8B-aligned
      Bhi[cb][ks] = *reinterpret_cast<const uint2*>(bp + 4);
    }
  }

  // ---- gating for this image (VALU work overlaps the B-load latency) ----
  const float gi0 = g_gateinp[b * 3 + 0];
  const float gi1 = g_gateinp[b * 3 + 1];
  const float gi2 = g_gateinp[b * 3 + 2];
  float best1 = -1e30f, best2 = -1e30f;
  int i1 = 0, i2 = 0;
  #pragma unroll
  for (int e = 0; e < NEXP; ++e) {
    const float lg = gi0 * w_gate[e] + gi1 * w_gate[8 + e] + gi2 * w_gate[16 + e];
    if (lg > best1) { best2 = best1; i2 = i1; best1 = lg; i1 = e; }
    else if (lg > best2) { best2 = lg; i2 = e; }
  }
  const float e21 = expf(best2 - best1);
  const float g1 = 1.f / (1.f + e21);
  const float g2 = e21 / (1.f + e21);
  const int e1 = __builtin_amdgcn_readfirstlane(i1);
  const int e2 = __builtin_amdgcn_readfirstlane(i2);

  // ---- burst 2: A-fragment loads (need e1/e2) ----
  const int wbase = w * 16;
  const int eidx[3] = {e1, e2, 8};
  bf16x8 af[3][NKS];
  #pragma unroll
  for (int e = 0; e < 3; ++e) {
    const ushort* ape = g_pw2 + ((size_t)(eidx[e] * COUT + wbase + colA)) * KPAD2 + m * 8;
    #pragma unroll
    for (int ks = 0; ks < NKS; ++ks)
      af[e][ks] = __builtin_bit_cast(bf16x8,
          *reinterpret_cast<const uint4*>(ape + ks * 32));
  }

  // ---- aux loss: block 0, wave 0 (lane = image) — overlaps A-load latency ----
  if (blockIdx.x == 0 && w == 0) {
    float mg1 = 0.f, mg2 = 0.f;
    int me1 = -1, me2 = -1;
    if (lane < BATCH) {
      const float a0 = g_gateinp[lane * 3 + 0];
      const float a1 = g_gateinp[lane * 3 + 1];
      const float a2 = g_gateinp[lane * 3 + 2];
      float b1 = -1e30f, b2 = -1e30f;
      int j1 = 0, j2 = 0;
      #pragma unroll
      for (int e = 0; e < NEXP; ++e) {
        const float lg = a0 * w_gate[e] + a1 * w_gate[8 + e] + a2 * w_gate[16 + e];
        if (lg > b1) { b2 = b1; j2 = j1; b1 = lg; j1 = e; }
        else if (lg > b2) { b2 = lg; j2 = e; }
      }
      const float q = expf(b2 - b1);
      mg1 = 1.f / (1.f + q); mg2 = q / (1.f + q);
      me1 = j1; me2 = j2;
    }
    float imp[NEXP], lod[NEXP];
    #pragma unroll
    for (int e = 0; e < NEXP; ++e) {
      float ie = ((me1 == e) ? mg1 : 0.f) + ((me2 == e) ? mg2 : 0.f);
      float le = (((me1 == e) && (mg1 > 0.f)) ? 1.f : 0.f)
               + (((me2 == e) && (mg2 > 0.f)) ? 1.f : 0.f);
      #pragma unroll
      for (int o = 32; o > 0; o >>= 1) { ie += __shfl_xor(ie, o, 64); le += __shfl_xor(le, o, 64); }
      imp[e] = ie; lod[e] = le;
    }
    if (lane == 0) {
      float mi = 0.f, ml = 0.f;
      #pragma unroll
      for (int e = 0; e < NEXP; ++e) { mi += imp[e]; ml += lod[e]; }
      mi *= (1.f / NEXP); ml *= (1.f / NEXP);
      float vi = 0.f, vl = 0.f;
      #pragma unroll
      for (int e = 0; e < NEXP; ++e) {
        const float di = imp[e] - mi; vi += di * di;
        const float dl = lod[e] - ml; vl += dl * dl;
      }
      vi *= (1.f / (NEXP - 1)); vl *= (1.f / (NEXP - 1));
      loss_out[0] = 0.01f * (vi / (mi * mi + 1e-10f) + vl / (ml * ml + 1e-10f));
    }
  }

  // ---- MFMA: all operands in registers, 12 independent acc chains ----
  f32x4 acc[4][3];
  #pragma unroll
  for (int cb = 0; cb < 4; ++cb)
    #pragma unroll
    for (int e = 0; e < 3; ++e) acc[cb][e] = (f32x4){0.f, 0.f, 0.f, 0.f};

  #pragma unroll
  for (int ks = 0; ks < NKS; ++ks) {
    #pragma unroll
    for (int cb = 0; cb < 4; ++cb) {
      const uint4 raw = {Blo[cb][ks].x, Blo[cb][ks].y, Bhi[cb][ks].x, Bhi[cb][ks].y};
      const bf16x8 bf = __builtin_bit_cast(bf16x8, raw);
      #pragma unroll
      for (int e = 0; e < 3; ++e)
        acc[cb][e] = __builtin_amdgcn_mfma_f32_16x16x32_bf16(af[e][ks], bf, acc[cb][e], 0, 0, 0);
    }
  }

  // ---- bias + per-pixel LN stats ----
  const int co0 = wbase + m * 4;
  const int col = colA;
  float4 bias[3];
  bias[0] = *reinterpret_cast<const float4*>(eB + e1 * COUT + co0);
  bias[1] = *reinterpret_cast<const float4*>(eB + e2 * COUT + co0);
  bias[2] = *reinterpret_cast<const float4*>(sB + co0);
  #pragma unroll
  for (int cb = 0; cb < 4; ++cb)
    #pragma unroll
    for (int e = 0; e < 3; ++e) {
      acc[cb][e][0] += (&bias[e].x)[0];
      acc[cb][e][1] += (&bias[e].x)[1];
      acc[cb][e][2] += (&bias[e].x)[2];
      acc[cb][e][3] += (&bias[e].x)[3];
    }

  #pragma unroll
  for (int cb = 0; cb < 4; ++cb)
    #pragma unroll
    for (int e = 0; e < 3; ++e) {
      float s = acc[cb][e][0] + acc[cb][e][1] + acc[cb][e][2] + acc[cb][e][3];
      float q = acc[cb][e][0] * acc[cb][e][0] + acc[cb][e][1] * acc[cb][e][1]
              + acc[cb][e][2] * acc[cb][e][2] + acc[cb][e][3] * acc[cb][e][3];
      s += __shfl_xor(s, 16, 64); s += __shfl_xor(s, 32, 64);
      q += __shfl_xor(q, 16, 64); q += __shfl_xor(q, 32, 64);
      if (lane < 16) Sstats[((w * 3 + e) * 4 + cb) * 16 + col] = make_float2(s, q);
    }
  __syncthreads();

  // ---- LN + gated combine + store ----
  float4 lw[3], lb[3];
  lw[0] = *reinterpret_cast<const float4*>(elnw + e1 * COUT + co0);
  lw[1] = *reinterpret_cast<const float4*>(elnw + e2 * COUT + co0);
  lw[2] = *reinterpret_cast<const float4*>(slnw + co0);
  lb[0] = *reinterpret_cast<const float4*>(elnb + e1 * COUT + co0);
  lb[1] = *reinterpret_cast<const float4*>(elnb + e2 * COUT + co0);
  lb[2] = *reinterpret_cast<const float4*>(slnb + co0);
  const float ge[3] = {g1, g2, 1.f};

  float* outb = out + (size_t)b * (COUT * NPIX) + t64;
  #pragma unroll
  for (int cb = 0; cb < 4; ++cb) {
    float u[3], rr[3];
    #pragma unroll
    for (int e = 0; e < 3; ++e) {
      float s = 0.f, q = 0.f;
      #pragma unroll
      for (int ww = 0; ww < 4; ++ww) {
        const float2 sq = Sstats[((ww * 3 + e) * 4 + cb) * 16 + col];
        s += sq.x; q += sq.y;
      }
      u[e] = s * (1.f / 64.f);
      const float var = q * (1.f / 64.f) - u[e] * u[e];
      rr[e] = rsqrtf(var + LN_EPS_F);
    }
    #pragma unroll
    for (int reg = 0; reg < 4; ++reg) {
      float o = 0.f;
      #pragma unroll
      for (int e = 0; e < 3; ++e) {
        const float y = acc[cb][e][reg];
        o += ge[e] * ((&lw[e].x)[reg] * (y - u[e]) * rr[e] + (&lb[e].x)[reg]);
      }
      outb[(size_t)(co0 + reg) * NPIX + cb * 16 + col] = o;
    }
  }
}

// ---------------- launch ----------------
extern "C" void kernel_launch(void* const* d_in, const int* in_sizes, int n_in,
                              void* d_out, int out_size, void* d_ws, size_t ws_size,
                              hipStream_t stream) {
  const float* x    = (const float*)d_in[0];
  const float* eW   = (const float*)d_in[1];
  const float* eB   = (const float*)d_in[2];
  const float* elnw = (const float*)d_in[3];
  const float* elnb = (const float*)d_in[4];
  const float* sW   = (const float*)d_in[5];
  const float* sB   = (const float*)d_in[6];
  const float* slnw = (const float*)d_in[7];
  const float* slnb = (const float*)d_in[8];
  const float* wg   = (const float*)d_in[9];
  float* out = (float*)d_out;

  float* loss_ptr = out + (size_t)BATCH * COUT * NPIX;  // element 6422528

  k_pre<<<N_CONV + N_GATE + N_REPACK, 256, 0, stream>>>(x, eW, sW);
  k_main<<<BATCH * (NPIX / 64), 256, 0, stream>>>(wg, eB, sB, elnw, elnb,
                                                  slnw, slnb, out, loss_ptr);
}

// Round 8
// 61.714 us; speedup vs baseline: 1.1421x; 1.1421x over previous
//
#include <hip/hip_runtime.h>
#include <cstdint>
#include <cstddef>

// ---- problem constants ----
static constexpr int BATCH = 32;
static constexpr int CIN   = 3;
static constexpr int HIN   = 224, WIN = 224;
static constexpr int COUT  = 64;
static constexpr int HOUT  = 56, WOUT = 56;
static constexpr int NPIX  = HOUT * WOUT;     // 3136 = 49*64
static constexpr int NEXP  = 8;
static constexpr int PH    = 227;             // padded rows: 3 zero rows on top
static constexpr int PW    = 232;             // 3 left pad + 224 + 5 right pad
static constexpr int KROWS = 21;              // ci*7 + kh
static constexpr int KPAD2 = 192;             // 24 rows * 8 slots
static constexpr int NKS   = 6;               // K-steps of 32
static constexpr float LN_EPS_F = 1e-6f;

// k_pre role partition
static constexpr int CONV_SLICES = 16;
static constexpr int ROWS_PER_SLICE = 15;     // 16*15 = 240 >= 227
static constexpr int N_CONV = BATCH * CIN * CONV_SLICES;          // 1536
static constexpr int N_GATE = BATCH * CIN;                        // 96
static constexpr int N_REPACK = (9 * COUT * KPAD2 + 255) / 256;   // 432

typedef __bf16 bf16x8 __attribute__((ext_vector_type(8)));
typedef float  f32x4  __attribute__((ext_vector_type(4)));

// ---- device-global scratch ----
__device__ __align__(16) ushort g_xbf[BATCH * CIN * PH * PW];  // padded bf16 x (~10.1 MB)
__device__ __align__(16) ushort g_pw2[9 * COUT * KPAD2];       // bf16 weights, k' layout
__device__ float g_gateinp[BATCH * CIN];

__device__ __forceinline__ ushort f2bf(float f) {
  uint u = __float_as_uint(f);
  uint r = (u + 0x7FFFu + ((u >> 16) & 1u)) >> 16;             // RNE
  return (ushort)r;
}

// ---------------- kernel 1: fused convert (0..1535) / gate_mean (1536..1631) /
//                             repack (1632..2063) ----------------
__global__ __launch_bounds__(256) void k_pre(const float* __restrict__ x,
                                             const float* __restrict__ eW,
                                             const float* __restrict__ sW) {
  const int bid = blockIdx.x;
  if (bid < N_CONV) {
    const int plane = bid / CONV_SLICES;
    const int slice = bid - plane * CONV_SLICES;
    const float* __restrict__ src = x + (size_t)plane * (HIN * WIN);
    uint* __restrict__ dst = reinterpret_cast<uint*>(g_xbf + (size_t)plane * (PH * PW));
    const int i0 = slice * (ROWS_PER_SLICE * (PW / 2));
    const int iN = PH * (PW / 2);
    const int i1 = (i0 + ROWS_PER_SLICE * (PW / 2) < iN) ? i0 + ROWS_PER_SLICE * (PW / 2) : iN;
    for (int i = i0 + (int)threadIdx.x; i < i1; i += 256) {
      const int r = i / (PW / 2);
      const int j = i - r * (PW / 2);
      uint o = 0u;
      if (r >= 3) {
        const int ih = r - 3;
        const int c0 = 2 * j - 3;
        const int c1 = 2 * j - 2;
        const float f0 = ((unsigned)c0 < (unsigned)WIN) ? src[ih * WIN + c0] : 0.f;
        const float f1 = ((unsigned)c1 < (unsigned)WIN) ? src[ih * WIN + c1] : 0.f;
        o = (uint)f2bf(f0) | ((uint)f2bf(f1) << 16);
      }
      dst[i] = o;
    }
  } else if (bid < N_CONV + N_GATE) {
    const int plane = bid - N_CONV;
    const float4* p4 = reinterpret_cast<const float4*>(x + (size_t)plane * (HIN * WIN));
    float s = 0.f;
    for (int i = threadIdx.x; i < (HIN * WIN) / 4; i += 256) {
      const float4 v = p4[i];
      s += v.x + v.y + v.z + v.w;
    }
    __shared__ float red[256];
    red[threadIdx.x] = s;
    __syncthreads();
    for (int off = 128; off > 0; off >>= 1) {
      if ((int)threadIdx.x < off) red[threadIdx.x] += red[threadIdx.x + off];
      __syncthreads();
    }
    if (threadIdx.x == 0) g_gateinp[plane] = red[0] * (1.f / (float)(HIN * WIN));
  } else {
    const int idx = (bid - N_CONV - N_GATE) * 256 + threadIdx.x;
    if (idx >= 9 * COUT * KPAD2) return;
    const int k2  = idx % KPAD2;
    const int coe = idx / KPAD2;    // e*64 + co
    const int co  = coe & 63;
    const int e   = coe >> 6;
    const int kw  = k2 & 7;
    const int row = k2 >> 3;
    float v = 0.f;
    if (kw < 7 && row < KROWS) {
      const int k = row * 7 + kw;
      v = (e < 8) ? eW[(size_t)coe * 147 + k] : sW[(size_t)co * 147 + k];
    }
    g_pw2[idx] = f2bf(v);
  }
}

// ---------------- kernel 2: MFMA conv + LN + gated combine (+gating +loss) ----------
// Block: 1 image x 64 pixels, 4 waves; wave w owns co slice [16w,16w+16).
// B staged ONCE per block into LDS [24 rows][64 px][8] (48 VMEM instrs/block,
// was 192); A in two half-bursts; stores transposed through LDS -> dwordx4.
__global__ __launch_bounds__(256) void k_main(
    const float* __restrict__ w_gate,
    const float* __restrict__ eB, const float* __restrict__ sB,
    const float* __restrict__ elnw, const float* __restrict__ elnb,
    const float* __restrict__ slnw, const float* __restrict__ slnb,
    float* __restrict__ out, float* __restrict__ loss_out) {
  __shared__ __align__(16) ushort Bl[24 * 64 * 8];     // 24.5 KB B tile
  __shared__ float2 Sstats[4 * 3 * 4 * 16];            // 6 KB stats
  float* Trans = reinterpret_cast<float*>(Bl);         // 16 KB overlay (post-barrier)

  const int tid  = threadIdx.x;
  const int lane = tid & 63;
  const int w    = tid >> 6;
  const int b    = blockIdx.x / (NPIX / 64);
  const int t    = blockIdx.x % (NPIX / 64);
  const int t64  = t * 64;

  // gating inputs (issued first; tiny)
  const float gi0 = g_gateinp[b * 3 + 0];
  const float gi1 = g_gateinp[b * 3 + 1];
  const float gi2 = g_gateinp[b * 3 + 2];

  // ---- stage B tile: row r = 4*i + w, px = lane ----
  const ushort* __restrict__ bimg = g_xbf + (size_t)b * (CIN * PH * PW);
  {
    const int pg = t64 + lane;
    const int oh = pg / WOUT;
    const int ow = pg - oh * WOUT;
    const int sbase = (oh * 4) * PW + ow * 4;          // ushorts; byte-addr 8B-aligned
    #pragma unroll
    for (int i = 0; i < 6; ++i) {
      const int r  = 4 * i + w;                        // 0..23
      const int rr = r > 20 ? 20 : r;                  // rows 21..23: A is zero, any data ok
      const int ci = rr >= 14 ? 2 : (rr >= 7 ? 1 : 0);
      const int kh = rr - ci * 7;
      const ushort* sp = bimg + (ci * PH + kh) * PW + sbase;
      const uint2 lo = *reinterpret_cast<const uint2*>(sp);
      const uint2 hi = *reinterpret_cast<const uint2*>(sp + 4);
      uint4 q; q.x = lo.x; q.y = lo.y; q.z = hi.x; q.w = hi.y;
      *reinterpret_cast<uint4*>(&Bl[(r * 64 + lane) * 8]) = q;
    }
  }

  // ---- gating (overlaps staging-load latency) ----
  float best1 = -1e30f, best2 = -1e30f;
  int i1 = 0, i2 = 0;
  #pragma unroll
  for (int e = 0; e < NEXP; ++e) {
    const float lg = gi0 * w_gate[e] + gi1 * w_gate[8 + e] + gi2 * w_gate[16 + e];
    if (lg > best1) { best2 = best1; i2 = i1; best1 = lg; i1 = e; }
    else if (lg > best2) { best2 = lg; i2 = e; }
  }
  const float e21 = expf(best2 - best1);
  const float g1 = 1.f / (1.f + e21);
  const float g2 = e21 / (1.f + e21);
  const int e1 = __builtin_amdgcn_readfirstlane(i1);
  const int e2 = __builtin_amdgcn_readfirstlane(i2);

  const int m    = lane >> 4;
  const int colA = lane & 15;
  const int wbase = w * 16;
  const int eidx[3] = {e1, e2, 8};

  // ---- A half-burst 1 (ks 0..2) ----
  bf16x8 af1[3][3];
  #pragma unroll
  for (int e = 0; e < 3; ++e) {
    const ushort* ape = g_pw2 + ((size_t)(eidx[e] * COUT + wbase + colA)) * KPAD2 + m * 8;
    #pragma unroll
    for (int ks = 0; ks < 3; ++ks)
      af1[e][ks] = __builtin_bit_cast(bf16x8, *reinterpret_cast<const uint4*>(ape + ks * 32));
  }

  // ---- aux loss: block 0, wave 0 ----
  if (blockIdx.x == 0 && w == 0) {
    float mg1 = 0.f, mg2 = 0.f;
    int me1 = -1, me2 = -1;
    if (lane < BATCH) {
      const float a0 = g_gateinp[lane * 3 + 0];
      const float a1 = g_gateinp[lane * 3 + 1];
      const float a2 = g_gateinp[lane * 3 + 2];
      float b1 = -1e30f, b2 = -1e30f;
      int j1 = 0, j2 = 0;
      #pragma unroll
      for (int e = 0; e < NEXP; ++e) {
        const float lg = a0 * w_gate[e] + a1 * w_gate[8 + e] + a2 * w_gate[16 + e];
        if (lg > b1) { b2 = b1; j2 = j1; b1 = lg; j1 = e; }
        else if (lg > b2) { b2 = lg; j2 = e; }
      }
      const float q = expf(b2 - b1);
      mg1 = 1.f / (1.f + q); mg2 = q / (1.f + q);
      me1 = j1; me2 = j2;
    }
    float imp[NEXP], lod[NEXP];
    #pragma unroll
    for (int e = 0; e < NEXP; ++e) {
      float ie = ((me1 == e) ? mg1 : 0.f) + ((me2 == e) ? mg2 : 0.f);
      float le = (((me1 == e) && (mg1 > 0.f)) ? 1.f : 0.f)
               + (((me2 == e) && (mg2 > 0.f)) ? 1.f : 0.f);
      #pragma unroll
      for (int o = 32; o > 0; o >>= 1) { ie += __shfl_xor(ie, o, 64); le += __shfl_xor(le, o, 64); }
      imp[e] = ie; lod[e] = le;
    }
    if (lane == 0) {
      float mi = 0.f, ml = 0.f;
      #pragma unroll
      for (int e = 0; e < NEXP; ++e) { mi += imp[e]; ml += lod[e]; }
      mi *= (1.f / NEXP); ml *= (1.f / NEXP);
      float vi = 0.f, vl = 0.f;
      #pragma unroll
      for (int e = 0; e < NEXP; ++e) {
        const float di = imp[e] - mi; vi += di * di;
        const float dl = lod[e] - ml; vl += dl * dl;
      }
      vi *= (1.f / (NEXP - 1)); vl *= (1.f / (NEXP - 1));
      loss_out[0] = 0.01f * (vi / (mi * mi + 1e-10f) + vl / (ml * ml + 1e-10f));
    }
  }

  __syncthreads();   // B tile visible

  // ---- A half-burst 2 issued now; latency hides under first MFMA loop ----
  bf16x8 af2[3][3];
  #pragma unroll
  for (int e = 0; e < 3; ++e) {
    const ushort* ape = g_pw2 + ((size_t)(eidx[e] * COUT + wbase + colA)) * KPAD2 + m * 8;
    #pragma unroll
    for (int ks = 0; ks < 3; ++ks)
      af2[e][ks] = __builtin_bit_cast(bf16x8, *reinterpret_cast<const uint4*>(ape + (ks + 3) * 32));
  }

  f32x4 acc[4][3];
  #pragma unroll
  for (int cb = 0; cb < 4; ++cb)
    #pragma unroll
    for (int e = 0; e < 3; ++e) acc[cb][e] = (f32x4){0.f, 0.f, 0.f, 0.f};

  // ---- MFMA loop 1: ks 0..2 ----
  #pragma unroll
  for (int ks = 0; ks < 3; ++ks) {
    #pragma unroll
    for (int cb = 0; cb < 4; ++cb) {
      const int px = cb * 16 + colA;
      const bf16x8 bf = __builtin_bit_cast(bf16x8,
          *reinterpret_cast<const uint4*>(&Bl[((ks * 4 + m) * 64 + px) * 8]));
      #pragma unroll
      for (int e = 0; e < 3; ++e)
        acc[cb][e] = __builtin_amdgcn_mfma_f32_16x16x32_bf16(af1[e][ks], bf, acc[cb][e], 0, 0, 0);
    }
  }
  // ---- MFMA loop 2: ks 3..5 ----
  #pragma unroll
  for (int ks = 0; ks < 3; ++ks) {
    #pragma unroll
    for (int cb = 0; cb < 4; ++cb) {
      const int px = cb * 16 + colA;
      const bf16x8 bf = __builtin_bit_cast(bf16x8,
          *reinterpret_cast<const uint4*>(&Bl[(((ks + 3) * 4 + m) * 64 + px) * 8]));
      #pragma unroll
      for (int e = 0; e < 3; ++e)
        acc[cb][e] = __builtin_amdgcn_mfma_f32_16x16x32_bf16(af2[e][ks], bf, acc[cb][e], 0, 0, 0);
    }
  }

  // ---- bias + per-pixel LN stats ----
  const int co0 = wbase + m * 4;
  const int col = colA;
  float4 bias[3];
  bias[0] = *reinterpret_cast<const float4*>(eB + e1 * COUT + co0);
  bias[1] = *reinterpret_cast<const float4*>(eB + e2 * COUT + co0);
  bias[2] = *reinterpret_cast<const float4*>(sB + co0);
  #pragma unroll
  for (int cb = 0; cb < 4; ++cb)
    #pragma unroll
    for (int e = 0; e < 3; ++e) {
      acc[cb][e][0] += (&bias[e].x)[0];
      acc[cb][e][1] += (&bias[e].x)[1];
      acc[cb][e][2] += (&bias[e].x)[2];
      acc[cb][e][3] += (&bias[e].x)[3];
    }

  #pragma unroll
  for (int cb = 0; cb < 4; ++cb)
    #pragma unroll
    for (int e = 0; e < 3; ++e) {
      float s = acc[cb][e][0] + acc[cb][e][1] + acc[cb][e][2] + acc[cb][e][3];
      float q = acc[cb][e][0] * acc[cb][e][0] + acc[cb][e][1] * acc[cb][e][1]
              + acc[cb][e][2] * acc[cb][e][2] + acc[cb][e][3] * acc[cb][e][3];
      s += __shfl_xor(s, 16, 64); s += __shfl_xor(s, 32, 64);
      q += __shfl_xor(q, 16, 64); q += __shfl_xor(q, 32, 64);
      if (lane < 16) Sstats[((w * 3 + e) * 4 + cb) * 16 + col] = make_float2(s, q);
    }
  __syncthreads();   // stats visible; all B reads done -> Trans overlay safe

  // ---- LN + gated combine -> LDS transpose ----
  float4 lw[3], lb[3];
  lw[0] = *reinterpret_cast<const float4*>(elnw + e1 * COUT + co0);
  lw[1] = *reinterpret_cast<const float4*>(elnw + e2 * COUT + co0);
  lw[2] = *reinterpret_cast<const float4*>(slnw + co0);
  lb[0] = *reinterpret_cast<const float4*>(elnb + e1 * COUT + co0);
  lb[1] = *reinterpret_cast<const float4*>(elnb + e2 * COUT + co0);
  lb[2] = *reinterpret_cast<const float4*>(slnb + co0);
  const float ge[3] = {g1, g2, 1.f};

  #pragma unroll
  for (int cb = 0; cb < 4; ++cb) {
    float u[3], rr[3];
    #pragma unroll
    for (int e = 0; e < 3; ++e) {
      float s = 0.f, q = 0.f;
      #pragma unroll
      for (int ww = 0; ww < 4; ++ww) {
        const float2 sq = Sstats[((ww * 3 + e) * 4 + cb) * 16 + col];
        s += sq.x; q += sq.y;
      }
      u[e] = s * (1.f / 64.f);
      const float var = q * (1.f / 64.f) - u[e] * u[e];
      rr[e] = rsqrtf(var + LN_EPS_F);
    }
    #pragma unroll
    for (int reg = 0; reg < 4; ++reg) {
      float o = 0.f;
      #pragma unroll
      for (int e = 0; e < 3; ++e) {
        const float y = acc[cb][e][reg];
        o += ge[e] * ((&lw[e].x)[reg] * (y - u[e]) * rr[e] + (&lb[e].x)[reg]);
      }
      Trans[(co0 + reg) * 64 + cb * 16 + col] = o;
    }
  }
  __syncthreads();

  // ---- coalesced dwordx4 stores: thread -> (co = tid>>2, quarter = tid&3) ----
  {
    float* outb = out + (size_t)b * (COUT * NPIX) + t64;
    const int co = tid >> 2;
    const int qp = tid & 3;
    #pragma unroll
    for (int j = 0; j < 4; ++j) {
      const float4 v = *reinterpret_cast<const float4*>(&Trans[co * 64 + qp * 16 + j * 4]);
      *reinterpret_cast<float4*>(outb + (size_t)co * NPIX + qp * 16 + j * 4) = v;
    }
  }
}

// ---------------- launch ----------------
extern "C" void kernel_launch(void* const* d_in, const int* in_sizes, int n_in,
                              void* d_out, int out_size, void* d_ws, size_t ws_size,
                              hipStream_t stream) {
  const float* x    = (const float*)d_in[0];
  const float* eW   = (const float*)d_in[1];
  const float* eB   = (const float*)d_in[2];
  const float* elnw = (const float*)d_in[3];
  const float* elnb = (const float*)d_in[4];
  const float* sW   = (const float*)d_in[5];
  const float* sB   = (const float*)d_in[6];
  const float* slnw = (const float*)d_in[7];
  const float* slnb = (const float*)d_in[8];
  const float* wg   = (const float*)d_in[9];
  float* out = (float*)d_out;

  float* loss_ptr = out + (size_t)BATCH * COUT * NPIX;  // element 6422528

  k_pre<<<N_CONV + N_GATE + N_REPACK, 256, 0, stream>>>(x, eW, sW);
  k_main<<<BATCH * (NPIX / 64), 256, 0, stream>>>(wg, eB, sB, elnw, elnb,
                                                  slnw, slnb, out, loss_ptr);
}

// Round 9
// 58.829 us; speedup vs baseline: 1.1981x; 1.0490x over previous
//
#include <hip/hip_runtime.h>
#include <cstdint>
#include <cstddef>

// ---- problem constants ----
static constexpr int BATCH = 32;
static constexpr int CIN   = 3;
static constexpr int HIN   = 224, WIN = 224;
static constexpr int COUT  = 64;
static constexpr int HOUT  = 56, WOUT = 56;
static constexpr int NPIX  = HOUT * WOUT;     // 3136 = 49*64
static constexpr int NEXP  = 8;
static constexpr int PH    = 227;             // padded rows: 3 zero rows on top
static constexpr int PW    = 232;             // 3 left pad + 224 + 5 right pad
static constexpr int KROWS = 21;              // ci*7 + kh
static constexpr int KPAD2 = 192;             // 24 rows * 8 slots
static constexpr int NKS   = 6;               // K-steps of 32
static constexpr int TILES_PER_BLOCK = 7;     // 49 tiles/image = 7 blocks x 7 tiles
static constexpr float LN_EPS_F = 1e-6f;

// k_pre role partition
static constexpr int CONV_SLICES = 16;
static constexpr int ROWS_PER_SLICE = 15;     // 16*15 = 240 >= 227
static constexpr int N_CONV = BATCH * CIN * CONV_SLICES;          // 1536
static constexpr int N_GATE = BATCH * CIN;                        // 96
static constexpr int N_REPACK = (9 * COUT * KPAD2 + 255) / 256;   // 432

typedef __bf16 bf16x8 __attribute__((ext_vector_type(8)));
typedef float  f32x4  __attribute__((ext_vector_type(4)));

// ---- device-global scratch ----
__device__ __align__(16) ushort g_xbf[BATCH * CIN * PH * PW];  // padded bf16 x (~10.1 MB)
__device__ __align__(16) ushort g_pw2[9 * COUT * KPAD2];       // bf16 weights, k' layout
__device__ float g_gateinp[BATCH * CIN];

__device__ __forceinline__ ushort f2bf(float f) {
  uint u = __float_as_uint(f);
  uint r = (u + 0x7FFFu + ((u >> 16) & 1u)) >> 16;             // RNE
  return (ushort)r;
}

// ---------------- kernel 1: fused convert (0..1535) / gate_mean (1536..1631) /
//                             repack (1632..2063) ----------------
__global__ __launch_bounds__(256) void k_pre(const float* __restrict__ x,
                                             const float* __restrict__ eW,
                                             const float* __restrict__ sW) {
  const int bid = blockIdx.x;
  if (bid < N_CONV) {
    const int plane = bid / CONV_SLICES;
    const int slice = bid - plane * CONV_SLICES;
    const float* __restrict__ src = x + (size_t)plane * (HIN * WIN);
    uint* __restrict__ dst = reinterpret_cast<uint*>(g_xbf + (size_t)plane * (PH * PW));
    const int i0 = slice * (ROWS_PER_SLICE * (PW / 2));
    const int iN = PH * (PW / 2);
    const int i1 = (i0 + ROWS_PER_SLICE * (PW / 2) < iN) ? i0 + ROWS_PER_SLICE * (PW / 2) : iN;
    for (int i = i0 + (int)threadIdx.x; i < i1; i += 256) {
      const int r = i / (PW / 2);
      const int j = i - r * (PW / 2);
      uint o = 0u;
      if (r >= 3) {
        const int ih = r - 3;
        const int c0 = 2 * j - 3;
        const int c1 = 2 * j - 2;
        const float f0 = ((unsigned)c0 < (unsigned)WIN) ? src[ih * WIN + c0] : 0.f;
        const float f1 = ((unsigned)c1 < (unsigned)WIN) ? src[ih * WIN + c1] : 0.f;
        o = (uint)f2bf(f0) | ((uint)f2bf(f1) << 16);
      }
      dst[i] = o;
    }
  } else if (bid < N_CONV + N_GATE) {
    const int plane = bid - N_CONV;
    const float4* p4 = reinterpret_cast<const float4*>(x + (size_t)plane * (HIN * WIN));
    float s = 0.f;
    for (int i = threadIdx.x; i < (HIN * WIN) / 4; i += 256) {
      const float4 v = p4[i];
      s += v.x + v.y + v.z + v.w;
    }
    __shared__ float red[256];
    red[threadIdx.x] = s;
    __syncthreads();
    for (int off = 128; off > 0; off >>= 1) {
      if ((int)threadIdx.x < off) red[threadIdx.x] += red[threadIdx.x + off];
      __syncthreads();
    }
    if (threadIdx.x == 0) g_gateinp[plane] = red[0] * (1.f / (float)(HIN * WIN));
  } else {
    const int idx = (bid - N_CONV - N_GATE) * 256 + threadIdx.x;
    if (idx >= 9 * COUT * KPAD2) return;
    const int k2  = idx % KPAD2;
    const int coe = idx / KPAD2;    // e*64 + co
    const int co  = coe & 63;
    const int e   = coe >> 6;
    const int kw  = k2 & 7;
    const int row = k2 >> 3;
    float v = 0.f;
    if (kw < 7 && row < KROWS) {
      const int k = row * 7 + kw;
      v = (e < 8) ? eW[(size_t)coe * 147 + k] : sW[(size_t)co * 147 + k];
    }
    g_pw2[idx] = f2bf(v);
  }
}

// ---------------- kernel 2: fat-block MFMA conv + LN + gated combine ----------
// 224 blocks (<=1/CU): block = (image b, group g); processes 7 consecutive
// 64-pixel tiles with double-buffered LDS B staging. A-fragments, bias, LN
// params, gating loaded ONCE per block. Epilogue identical to R8.
__global__ __launch_bounds__(256, 1) void k_main(
    const float* __restrict__ w_gate,
    const float* __restrict__ eB, const float* __restrict__ sB,
    const float* __restrict__ elnw, const float* __restrict__ elnb,
    const float* __restrict__ slnw, const float* __restrict__ slnb,
    float* __restrict__ out, float* __restrict__ loss_out) {
  __shared__ __align__(16) ushort Bl[2][24 * 64 * 8];  // 2 x 24.5 KB B tiles
  __shared__ float2 Sstats[4 * 3 * 4 * 16];            // 6 KB stats

  const int tid  = threadIdx.x;
  const int lane = tid & 63;
  const int w    = tid >> 6;
  const int b    = blockIdx.x / TILES_PER_BLOCK;
  const int g    = blockIdx.x % TILES_PER_BLOCK;

  const ushort* __restrict__ bimg = g_xbf + (size_t)b * (CIN * PH * PW);

  // per-(wave,row-slot) source row offsets (row r = 4*ii + w)
  int offs[6];
  #pragma unroll
  for (int ii = 0; ii < 6; ++ii) {
    const int r  = 4 * ii + w;
    const int rr = r > 20 ? 20 : r;            // rows 21..23: A is zero, any data ok
    const int ci = rr >= 14 ? 2 : (rr >= 7 ? 1 : 0);
    const int kh = rr - ci * 7;
    offs[ii] = (ci * PH + kh) * PW;
  }

  // ---- stage tile 0 into regs, write LDS buffer 0 ----
  uint4 sreg[6];
  {
    const int pg = (g * TILES_PER_BLOCK) * 64 + lane;
    const int oh = pg / WOUT;
    const int ow = pg - oh * WOUT;
    const int sbase = (oh * 4) * PW + ow * 4;
    #pragma unroll
    for (int ii = 0; ii < 6; ++ii) {
      const ushort* sp = bimg + offs[ii] + sbase;
      const uint2 lo = *reinterpret_cast<const uint2*>(sp);
      const uint2 hi = *reinterpret_cast<const uint2*>(sp + 4);
      sreg[ii].x = lo.x; sreg[ii].y = lo.y; sreg[ii].z = hi.x; sreg[ii].w = hi.y;
    }
  }

  // ---- gating (overlaps stage-load latency) ----
  const float gi0 = g_gateinp[b * 3 + 0];
  const float gi1 = g_gateinp[b * 3 + 1];
  const float gi2 = g_gateinp[b * 3 + 2];
  float best1 = -1e30f, best2 = -1e30f;
  int i1 = 0, i2 = 0;
  #pragma unroll
  for (int e = 0; e < NEXP; ++e) {
    const float lg = gi0 * w_gate[e] + gi1 * w_gate[8 + e] + gi2 * w_gate[16 + e];
    if (lg > best1) { best2 = best1; i2 = i1; best1 = lg; i1 = e; }
    else if (lg > best2) { best2 = lg; i2 = e; }
  }
  const float e21 = expf(best2 - best1);
  const float g1 = 1.f / (1.f + e21);
  const float g2 = e21 / (1.f + e21);
  const int e1 = __builtin_amdgcn_readfirstlane(i1);
  const int e2 = __builtin_amdgcn_readfirstlane(i2);

  const int m     = lane >> 4;
  const int colA  = lane & 15;
  const int wbase = w * 16;
  const int eidx[3] = {e1, e2, 8};

  // ---- A-fragments: once per block (3 experts x 6 K-steps) ----
  bf16x8 afrag[3][NKS];
  #pragma unroll
  for (int e = 0; e < 3; ++e) {
    const ushort* ape = g_pw2 + ((size_t)(eidx[e] * COUT + wbase + colA)) * KPAD2 + m * 8;
    #pragma unroll
    for (int ks = 0; ks < NKS; ++ks)
      afrag[e][ks] = __builtin_bit_cast(bf16x8, *reinterpret_cast<const uint4*>(ape + ks * 32));
  }

  // ---- block-invariant epilogue params ----
  const int co0 = wbase + m * 4;
  const int col = colA;
  float4 bias[3], lw[3], lb[3];
  bias[0] = *reinterpret_cast<const float4*>(eB + e1 * COUT + co0);
  bias[1] = *reinterpret_cast<const float4*>(eB + e2 * COUT + co0);
  bias[2] = *reinterpret_cast<const float4*>(sB + co0);
  lw[0] = *reinterpret_cast<const float4*>(elnw + e1 * COUT + co0);
  lw[1] = *reinterpret_cast<const float4*>(elnw + e2 * COUT + co0);
  lw[2] = *reinterpret_cast<const float4*>(slnw + co0);
  lb[0] = *reinterpret_cast<const float4*>(elnb + e1 * COUT + co0);
  lb[1] = *reinterpret_cast<const float4*>(elnb + e2 * COUT + co0);
  lb[2] = *reinterpret_cast<const float4*>(slnb + co0);
  const float ge[3] = {g1, g2, 1.f};

  // ---- aux loss: block 0, wave 0 ----
  if (blockIdx.x == 0 && w == 0) {
    float mg1 = 0.f, mg2 = 0.f;
    int me1 = -1, me2 = -1;
    if (lane < BATCH) {
      const float a0 = g_gateinp[lane * 3 + 0];
      const float a1 = g_gateinp[lane * 3 + 1];
      const float a2 = g_gateinp[lane * 3 + 2];
      float b1 = -1e30f, b2 = -1e30f;
      int j1 = 0, j2 = 0;
      #pragma unroll
      for (int e = 0; e < NEXP; ++e) {
        const float lg = a0 * w_gate[e] + a1 * w_gate[8 + e] + a2 * w_gate[16 + e];
        if (lg > b1) { b2 = b1; j2 = j1; b1 = lg; j1 = e; }
        else if (lg > b2) { b2 = lg; j2 = e; }
      }
      const float q = expf(b2 - b1);
      mg1 = 1.f / (1.f + q); mg2 = q / (1.f + q);
      me1 = j1; me2 = j2;
    }
    float imp[NEXP], lod[NEXP];
    #pragma unroll
    for (int e = 0; e < NEXP; ++e) {
      float ie = ((me1 == e) ? mg1 : 0.f) + ((me2 == e) ? mg2 : 0.f);
      float le = (((me1 == e) && (mg1 > 0.f)) ? 1.f : 0.f)
               + (((me2 == e) && (mg2 > 0.f)) ? 1.f : 0.f);
      #pragma unroll
      for (int o = 32; o > 0; o >>= 1) { ie += __shfl_xor(ie, o, 64); le += __shfl_xor(le, o, 64); }
      imp[e] = ie; lod[e] = le;
    }
    if (lane == 0) {
      float mi = 0.f, ml = 0.f;
      #pragma unroll
      for (int e = 0; e < NEXP; ++e) { mi += imp[e]; ml += lod[e]; }
      mi *= (1.f / NEXP); ml *= (1.f / NEXP);
      float vi = 0.f, vl = 0.f;
      #pragma unroll
      for (int e = 0; e < NEXP; ++e) {
        const float di = imp[e] - mi; vi += di * di;
        const float dl = lod[e] - ml; vl += dl * dl;
      }
      vi *= (1.f / (NEXP - 1)); vl *= (1.f / (NEXP - 1));
      loss_out[0] = 0.01f * (vi / (mi * mi + 1e-10f) + vl / (ml * ml + 1e-10f));
    }
  }

  // write prologue tile 0 into buffer 0
  #pragma unroll
  for (int ii = 0; ii < 6; ++ii)
    *reinterpret_cast<uint4*>(&Bl[0][((4 * ii + w) * 64 + lane) * 8]) = sreg[ii];

  // ---- main pipelined loop over 7 tiles ----
  for (int i = 0; i < TILES_PER_BLOCK; ++i) {
    const int c = i & 1;
    const int t = g * TILES_PER_BLOCK + i;

    // issue next tile's global loads NOW (hide under MFMA+epilogue)
    if (i < TILES_PER_BLOCK - 1) {
      const int pg = (t + 1) * 64 + lane;
      const int oh = pg / WOUT;
      const int ow = pg - oh * WOUT;
      const int sbase = (oh * 4) * PW + ow * 4;
      #pragma unroll
      for (int ii = 0; ii < 6; ++ii) {
        const ushort* sp = bimg + offs[ii] + sbase;
        const uint2 lo = *reinterpret_cast<const uint2*>(sp);
        const uint2 hi = *reinterpret_cast<const uint2*>(sp + 4);
        sreg[ii].x = lo.x; sreg[ii].y = lo.y; sreg[ii].z = hi.x; sreg[ii].w = hi.y;
      }
    }

    __syncthreads();   // Bl[c] (tile i) visible; prior Trans reads done

    // ---- MFMA: acc[cb][e] = W_e · B(tile i) ----
    f32x4 acc[4][3];
    #pragma unroll
    for (int cb = 0; cb < 4; ++cb)
      #pragma unroll
      for (int e = 0; e < 3; ++e) acc[cb][e] = (f32x4){0.f, 0.f, 0.f, 0.f};

    #pragma unroll
    for (int ks = 0; ks < NKS; ++ks) {
      #pragma unroll
      for (int cb = 0; cb < 4; ++cb) {
        const int px = cb * 16 + colA;
        const bf16x8 bf = __builtin_bit_cast(bf16x8,
            *reinterpret_cast<const uint4*>(&Bl[c][((ks * 4 + m) * 64 + px) * 8]));
        #pragma unroll
        for (int e = 0; e < 3; ++e)
          acc[cb][e] = __builtin_amdgcn_mfma_f32_16x16x32_bf16(afrag[e][ks], bf, acc[cb][e], 0, 0, 0);
      }
    }

    // ---- bias + per-pixel LN stats ----
    #pragma unroll
    for (int cb = 0; cb < 4; ++cb)
      #pragma unroll
      for (int e = 0; e < 3; ++e) {
        acc[cb][e][0] += (&bias[e].x)[0];
        acc[cb][e][1] += (&bias[e].x)[1];
        acc[cb][e][2] += (&bias[e].x)[2];
        acc[cb][e][3] += (&bias[e].x)[3];
      }

    #pragma unroll
    for (int cb = 0; cb < 4; ++cb)
      #pragma unroll
      for (int e = 0; e < 3; ++e) {
        float s = acc[cb][e][0] + acc[cb][e][1] + acc[cb][e][2] + acc[cb][e][3];
        float q = acc[cb][e][0] * acc[cb][e][0] + acc[cb][e][1] * acc[cb][e][1]
                + acc[cb][e][2] * acc[cb][e][2] + acc[cb][e][3] * acc[cb][e][3];
        s += __shfl_xor(s, 16, 64); s += __shfl_xor(s, 32, 64);
        q += __shfl_xor(q, 16, 64); q += __shfl_xor(q, 32, 64);
        if (lane < 16) Sstats[((w * 3 + e) * 4 + cb) * 16 + col] = make_float2(s, q);
      }
    __syncthreads();   // stats visible; all MFMA reads of Bl[c] done

    // ---- LN + gated combine -> LDS transpose (overlay on Bl[c]) ----
    float* Trans = reinterpret_cast<float*>(&Bl[c][0]);
    #pragma unroll
    for (int cb = 0; cb < 4; ++cb) {
      float u[3], rr[3];
      #pragma unroll
      for (int e = 0; e < 3; ++e) {
        float s = 0.f, q = 0.f;
        #pragma unroll
        for (int ww = 0; ww < 4; ++ww) {
          const float2 sq = Sstats[((ww * 3 + e) * 4 + cb) * 16 + col];
          s += sq.x; q += sq.y;
        }
        u[e] = s * (1.f / 64.f);
        const float var = q * (1.f / 64.f) - u[e] * u[e];
        rr[e] = rsqrtf(var + LN_EPS_F);
      }
      #pragma unroll
      for (int reg = 0; reg < 4; ++reg) {
        float o = 0.f;
        #pragma unroll
        for (int e = 0; e < 3; ++e) {
          const float y = acc[cb][e][reg];
          o += ge[e] * ((&lw[e].x)[reg] * (y - u[e]) * rr[e] + (&lb[e].x)[reg]);
        }
        Trans[(co0 + reg) * 64 + cb * 16 + col] = o;
      }
    }
    __syncthreads();

    // ---- coalesced dwordx4 stores ----
    {
      float* outb = out + (size_t)b * (COUT * NPIX) + t * 64;
      const int co = tid >> 2;
      const int qp = tid & 3;
      #pragma unroll
      for (int j = 0; j < 4; ++j) {
        const float4 v = *reinterpret_cast<const float4*>(&Trans[co * 64 + qp * 16 + j * 4]);
        *reinterpret_cast<float4*>(outb + (size_t)co * NPIX + qp * 16 + j * 4) = v;
      }
    }

    // ---- write next tile into the other buffer ----
    if (i < TILES_PER_BLOCK - 1) {
      #pragma unroll
      for (int ii = 0; ii < 6; ++ii)
        *reinterpret_cast<uint4*>(&Bl[c ^ 1][((4 * ii + w) * 64 + lane) * 8]) = sreg[ii];
    }
  }
}

// ---------------- launch ----------------
extern "C" void kernel_launch(void* const* d_in, const int* in_sizes, int n_in,
                              void* d_out, int out_size, void* d_ws, size_t ws_size,
                              hipStream_t stream) {
  const float* x    = (const float*)d_in[0];
  const float* eW   = (const float*)d_in[1];
  const float* eB   = (const float*)d_in[2];
  const float* elnw = (const float*)d_in[3];
  const float* elnb = (const float*)d_in[4];
  const float* sW   = (const float*)d_in[5];
  const float* sB   = (const float*)d_in[6];
  const float* slnw = (const float*)d_in[7];
  const float* slnb = (const float*)d_in[8];
  const float* wg   = (const float*)d_in[9];
  float* out = (float*)d_out;

  float* loss_ptr = out + (size_t)BATCH * COUT * NPIX;  // element 6422528

  k_pre<<<N_CONV + N_GATE + N_REPACK, 256, 0, stream>>>(x, eW, sW);
  k_main<<<BATCH * TILES_PER_BLOCK, 256, 0, stream>>>(wg, eB, sB, elnw, elnb,
                                                      slnw, slnb, out, loss_ptr);
}

// Round 10
// 55.421 us; speedup vs baseline: 1.2718x; 1.0615x over previous
//
#include <hip/hip_runtime.h>
#include <cstdint>
#include <cstddef>

// ---- problem constants ----
static constexpr int BATCH = 32;
static constexpr int CIN   = 3;
static constexpr int HIN   = 224, WIN = 224;
static constexpr int COUT  = 64;
static constexpr int HOUT  = 56, WOUT = 56;
static constexpr int NPIX  = HOUT * WOUT;     // 3136 = 49*64
static constexpr int NEXP  = 8;
static constexpr int PH    = 227;             // padded rows: 3 zero rows on top
static constexpr int PW    = 232;             // 3 left pad + 224 + 5 right pad
static constexpr int KROWS = 21;              // ci*7 + kh
static constexpr int KPAD2 = 192;             // 24 rows * 8 slots
static constexpr int NKS   = 6;               // K-steps of 32
static constexpr int TILES_PER_BLOCK = 7;     // 49 tiles/image = 7 blocks x 7 tiles
static constexpr float LN_EPS_F = 1e-6f;

// k_pre role partition
static constexpr int CONV_SLICES = 16;
static constexpr int ROWS_PER_SLICE = 15;     // 16*15 = 240 >= 227
static constexpr int N_CONV = BATCH * CIN * CONV_SLICES;          // 1536
static constexpr int N_GATE = BATCH * CIN;                        // 96
static constexpr int N_REPACK = (9 * COUT * KPAD2 + 255) / 256;   // 432

typedef __bf16 bf16x8 __attribute__((ext_vector_type(8)));
typedef float  f32x4  __attribute__((ext_vector_type(4)));

// ---- device-global scratch ----
__device__ __align__(16) ushort g_xbf[BATCH * CIN * PH * PW];  // padded bf16 x (~10.1 MB)
__device__ __align__(16) ushort g_pw2[9 * COUT * KPAD2];       // bf16 weights, k' layout
__device__ float g_gateinp[BATCH * CIN];

__device__ __forceinline__ ushort f2bf(float f) {
  uint u = __float_as_uint(f);
  uint r = (u + 0x7FFFu + ((u >> 16) & 1u)) >> 16;             // RNE
  return (ushort)r;
}

// LDS-visibility-only barrier: drains LDS ops, leaves global loads in flight.
// (__syncthreads would emit s_waitcnt vmcnt(0) and kill cross-tile prefetch.)
__device__ __forceinline__ void barrier_lgkm() {
  asm volatile("s_waitcnt lgkmcnt(0)" ::: "memory");
  __builtin_amdgcn_s_barrier();
  __builtin_amdgcn_sched_barrier(0);
}

// ---------------- kernel 1: fused convert (0..1535) / gate_mean (1536..1631) /
//                             repack (1632..2063) ----------------
__global__ __launch_bounds__(256) void k_pre(const float* __restrict__ x,
                                             const float* __restrict__ eW,
                                             const float* __restrict__ sW) {
  const int bid = blockIdx.x;
  if (bid < N_CONV) {
    const int plane = bid / CONV_SLICES;
    const int slice = bid - plane * CONV_SLICES;
    const float* __restrict__ src = x + (size_t)plane * (HIN * WIN);
    uint* __restrict__ dst = reinterpret_cast<uint*>(g_xbf + (size_t)plane * (PH * PW));
    const int i0 = slice * (ROWS_PER_SLICE * (PW / 2));
    const int iN = PH * (PW / 2);
    const int i1 = (i0 + ROWS_PER_SLICE * (PW / 2) < iN) ? i0 + ROWS_PER_SLICE * (PW / 2) : iN;
    for (int i = i0 + (int)threadIdx.x; i < i1; i += 256) {
      const int r = i / (PW / 2);
      const int j = i - r * (PW / 2);
      uint o = 0u;
      if (r >= 3) {
        const int ih = r - 3;
        const int c0 = 2 * j - 3;
        const int c1 = 2 * j - 2;
        const float f0 = ((unsigned)c0 < (unsigned)WIN) ? src[ih * WIN + c0] : 0.f;
        const float f1 = ((unsigned)c1 < (unsigned)WIN) ? src[ih * WIN + c1] : 0.f;
        o = (uint)f2bf(f0) | ((uint)f2bf(f1) << 16);
      }
      dst[i] = o;
    }
  } else if (bid < N_CONV + N_GATE) {
    const int plane = bid - N_CONV;
    const float4* p4 = reinterpret_cast<const float4*>(x + (size_t)plane * (HIN * WIN));
    float s = 0.f;
    for (int i = threadIdx.x; i < (HIN * WIN) / 4; i += 256) {
      const float4 v = p4[i];
      s += v.x + v.y + v.z + v.w;
    }
    __shared__ float red[256];
    red[threadIdx.x] = s;
    __syncthreads();
    for (int off = 128; off > 0; off >>= 1) {
      if ((int)threadIdx.x < off) red[threadIdx.x] += red[threadIdx.x + off];
      __syncthreads();
    }
    if (threadIdx.x == 0) g_gateinp[plane] = red[0] * (1.f / (float)(HIN * WIN));
  } else {
    const int idx = (bid - N_CONV - N_GATE) * 256 + threadIdx.x;
    if (idx >= 9 * COUT * KPAD2) return;
    const int k2  = idx % KPAD2;
    const int coe = idx / KPAD2;    // e*64 + co
    const int co  = coe & 63;
    const int e   = coe >> 6;
    const int kw  = k2 & 7;
    const int row = k2 >> 3;
    float v = 0.f;
    if (kw < 7 && row < KROWS) {
      const int k = row * 7 + kw;
      v = (e < 8) ? eW[(size_t)coe * 147 + k] : sW[(size_t)co * 147 + k];
    }
    g_pw2[idx] = f2bf(v);
  }
}

// ---------------- kernel 2: fat-block MFMA conv + LN + gated combine ----------
// 224 blocks; block = (image b, group g); 7 tiles, double-buffered LDS B.
// In-loop barriers are lgkm-only so cross-tile global prefetch stays in flight.
__global__ __launch_bounds__(256, 1) void k_main(
    const float* __restrict__ w_gate,
    const float* __restrict__ eB, const float* __restrict__ sB,
    const float* __restrict__ elnw, const float* __restrict__ elnb,
    const float* __restrict__ slnw, const float* __restrict__ slnb,
    float* __restrict__ out, float* __restrict__ loss_out) {
  __shared__ __align__(16) ushort Bl[2][24 * 64 * 8];  // 2 x 24 KB B tiles
  __shared__ float2 Sstats[2][4 * 3 * 4 * 16];         // 2 x 6 KB stats (tile parity)

  const int tid  = threadIdx.x;
  const int lane = tid & 63;
  const int w    = tid >> 6;
  const int b    = blockIdx.x / TILES_PER_BLOCK;
  const int g    = blockIdx.x % TILES_PER_BLOCK;

  const ushort* __restrict__ bimg = g_xbf + (size_t)b * (CIN * PH * PW);

  // per-(wave,row-slot) source row offsets (row r = 4*ii + w)
  int offs[6];
  #pragma unroll
  for (int ii = 0; ii < 6; ++ii) {
    const int r  = 4 * ii + w;
    const int rr = r > 20 ? 20 : r;            // rows 21..23: A is zero, any data ok
    const int ci = rr >= 14 ? 2 : (rr >= 7 ? 1 : 0);
    const int kh = rr - ci * 7;
    offs[ii] = (ci * PH + kh) * PW;
  }

  // ---- stage tile 0 into regs ----
  uint4 sreg[6];
  {
    const int pg = (g * TILES_PER_BLOCK) * 64 + lane;
    const int oh = pg / WOUT;
    const int ow = pg - oh * WOUT;
    const int sbase = (oh * 4) * PW + ow * 4;
    #pragma unroll
    for (int ii = 0; ii < 6; ++ii) {
      const ushort* sp = bimg + offs[ii] + sbase;
      const uint2 lo = *reinterpret_cast<const uint2*>(sp);
      const uint2 hi = *reinterpret_cast<const uint2*>(sp + 4);
      sreg[ii].x = lo.x; sreg[ii].y = lo.y; sreg[ii].z = hi.x; sreg[ii].w = hi.y;
    }
  }

  // ---- gating (overlaps stage-load latency) ----
  const float gi0 = g_gateinp[b * 3 + 0];
  const float gi1 = g_gateinp[b * 3 + 1];
  const float gi2 = g_gateinp[b * 3 + 2];
  float best1 = -1e30f, best2 = -1e30f;
  int i1 = 0, i2 = 0;
  #pragma unroll
  for (int e = 0; e < NEXP; ++e) {
    const float lg = gi0 * w_gate[e] + gi1 * w_gate[8 + e] + gi2 * w_gate[16 + e];
    if (lg > best1) { best2 = best1; i2 = i1; best1 = lg; i1 = e; }
    else if (lg > best2) { best2 = lg; i2 = e; }
  }
  const float e21 = expf(best2 - best1);
  const float g1 = 1.f / (1.f + e21);
  const float g2 = e21 / (1.f + e21);
  const int e1 = __builtin_amdgcn_readfirstlane(i1);
  const int e2 = __builtin_amdgcn_readfirstlane(i2);

  const int m     = lane >> 4;
  const int colA  = lane & 15;
  const int wbase = w * 16;
  const int eidx[3] = {e1, e2, 8};

  // ---- A-fragments: once per block (3 experts x 6 K-steps) ----
  bf16x8 afrag[3][NKS];
  #pragma unroll
  for (int e = 0; e < 3; ++e) {
    const ushort* ape = g_pw2 + ((size_t)(eidx[e] * COUT + wbase + colA)) * KPAD2 + m * 8;
    #pragma unroll
    for (int ks = 0; ks < NKS; ++ks)
      afrag[e][ks] = __builtin_bit_cast(bf16x8, *reinterpret_cast<const uint4*>(ape + ks * 32));
  }

  // ---- block-invariant epilogue params ----
  const int co0 = wbase + m * 4;
  const int col = colA;
  float4 bias[3], lw[3], lb[3];
  bias[0] = *reinterpret_cast<const float4*>(eB + e1 * COUT + co0);
  bias[1] = *reinterpret_cast<const float4*>(eB + e2 * COUT + co0);
  bias[2] = *reinterpret_cast<const float4*>(sB + co0);
  lw[0] = *reinterpret_cast<const float4*>(elnw + e1 * COUT + co0);
  lw[1] = *reinterpret_cast<const float4*>(elnw + e2 * COUT + co0);
  lw[2] = *reinterpret_cast<const float4*>(slnw + co0);
  lb[0] = *reinterpret_cast<const float4*>(elnb + e1 * COUT + co0);
  lb[1] = *reinterpret_cast<const float4*>(elnb + e2 * COUT + co0);
  lb[2] = *reinterpret_cast<const float4*>(slnb + co0);
  const float ge[3] = {g1, g2, 1.f};

  // ---- aux loss: block 0, wave 0 ----
  if (blockIdx.x == 0 && w == 0) {
    float mg1 = 0.f, mg2 = 0.f;
    int me1 = -1, me2 = -1;
    if (lane < BATCH) {
      const float a0 = g_gateinp[lane * 3 + 0];
      const float a1 = g_gateinp[lane * 3 + 1];
      const float a2 = g_gateinp[lane * 3 + 2];
      float b1 = -1e30f, b2 = -1e30f;
      int j1 = 0, j2 = 0;
      #pragma unroll
      for (int e = 0; e < NEXP; ++e) {
        const float lg = a0 * w_gate[e] + a1 * w_gate[8 + e] + a2 * w_gate[16 + e];
        if (lg > b1) { b2 = b1; j2 = j1; b1 = lg; j1 = e; }
        else if (lg > b2) { b2 = lg; j2 = e; }
      }
      const float q = expf(b2 - b1);
      mg1 = 1.f / (1.f + q); mg2 = q / (1.f + q);
      me1 = j1; me2 = j2;
    }
    float imp[NEXP], lod[NEXP];
    #pragma unroll
    for (int e = 0; e < NEXP; ++e) {
      float ie = ((me1 == e) ? mg1 : 0.f) + ((me2 == e) ? mg2 : 0.f);
      float le = (((me1 == e) && (mg1 > 0.f)) ? 1.f : 0.f)
               + (((me2 == e) && (mg2 > 0.f)) ? 1.f : 0.f);
      #pragma unroll
      for (int o = 32; o > 0; o >>= 1) { ie += __shfl_xor(ie, o, 64); le += __shfl_xor(le, o, 64); }
      imp[e] = ie; lod[e] = le;
    }
    if (lane == 0) {
      float mi = 0.f, ml = 0.f;
      #pragma unroll
      for (int e = 0; e < NEXP; ++e) { mi += imp[e]; ml += lod[e]; }
      mi *= (1.f / NEXP); ml *= (1.f / NEXP);
      float vi = 0.f, vl = 0.f;
      #pragma unroll
      for (int e = 0; e < NEXP; ++e) {
        const float di = imp[e] - mi; vi += di * di;
        const float dl = lod[e] - ml; vl += dl * dl;
      }
      vi *= (1.f / (NEXP - 1)); vl *= (1.f / (NEXP - 1));
      loss_out[0] = 0.01f * (vi / (mi * mi + 1e-10f) + vl / (ml * ml + 1e-10f));
    }
  }

  // write prologue tile 0 into buffer 0
  #pragma unroll
  for (int ii = 0; ii < 6; ++ii)
    *reinterpret_cast<uint4*>(&Bl[0][((4 * ii + w) * 64 + lane) * 8]) = sreg[ii];

  // ---- main pipelined loop over 7 tiles (2 lgkm-only barriers per tile) ----
  for (int i = 0; i < TILES_PER_BLOCK; ++i) {
    const int c  = i & 1;
    const int t  = g * TILES_PER_BLOCK + i;

    // issue next tile's global loads NOW; they stay in flight across barriers
    if (i < TILES_PER_BLOCK - 1) {
      const int pg = (t + 1) * 64 + lane;
      const int oh = pg / WOUT;
      const int ow = pg - oh * WOUT;
      const int sbase = (oh * 4) * PW + ow * 4;
      #pragma unroll
      for (int ii = 0; ii < 6; ++ii) {
        const ushort* sp = bimg + offs[ii] + sbase;
        const uint2 lo = *reinterpret_cast<const uint2*>(sp);
        const uint2 hi = *reinterpret_cast<const uint2*>(sp + 4);
        sreg[ii].x = lo.x; sreg[ii].y = lo.y; sreg[ii].z = hi.x; sreg[ii].w = hi.y;
      }
    }

    barrier_lgkm();   // Bl[c] (tile i) ds_writes visible; vmcnt NOT drained

    // ---- MFMA: acc[cb][e] = W_e · B(tile i) ----
    f32x4 acc[4][3];
    #pragma unroll
    for (int cb = 0; cb < 4; ++cb)
      #pragma unroll
      for (int e = 0; e < 3; ++e) acc[cb][e] = (f32x4){0.f, 0.f, 0.f, 0.f};

    #pragma unroll
    for (int ks = 0; ks < NKS; ++ks) {
      #pragma unroll
      for (int cb = 0; cb < 4; ++cb) {
        const int px = cb * 16 + colA;
        const bf16x8 bf = __builtin_bit_cast(bf16x8,
            *reinterpret_cast<const uint4*>(&Bl[c][((ks * 4 + m) * 64 + px) * 8]));
        #pragma unroll
        for (int e = 0; e < 3; ++e)
          acc[cb][e] = __builtin_amdgcn_mfma_f32_16x16x32_bf16(afrag[e][ks], bf, acc[cb][e], 0, 0, 0);
      }
    }

    // ---- bias + per-pixel LN stats (write parity buffer) ----
    #pragma unroll
    for (int cb = 0; cb < 4; ++cb)
      #pragma unroll
      for (int e = 0; e < 3; ++e) {
        acc[cb][e][0] += (&bias[e].x)[0];
        acc[cb][e][1] += (&bias[e].x)[1];
        acc[cb][e][2] += (&bias[e].x)[2];
        acc[cb][e][3] += (&bias[e].x)[3];
      }

    #pragma unroll
    for (int cb = 0; cb < 4; ++cb)
      #pragma unroll
      for (int e = 0; e < 3; ++e) {
        float s = acc[cb][e][0] + acc[cb][e][1] + acc[cb][e][2] + acc[cb][e][3];
        float q = acc[cb][e][0] * acc[cb][e][0] + acc[cb][e][1] * acc[cb][e][1]
                + acc[cb][e][2] * acc[cb][e][2] + acc[cb][e][3] * acc[cb][e][3];
        s += __shfl_xor(s, 16, 64); s += __shfl_xor(s, 32, 64);
        q += __shfl_xor(q, 16, 64); q += __shfl_xor(q, 32, 64);
        if (lane < 16) Sstats[c][((w * 3 + e) * 4 + cb) * 16 + col] = make_float2(s, q);
      }

    barrier_lgkm();   // stats visible; vmcnt (next-tile prefetch) still in flight

    // ---- LN + gated combine + direct stores ----
    float* outb = out + (size_t)b * (COUT * NPIX) + t * 64;
    #pragma unroll
    for (int cb = 0; cb < 4; ++cb) {
      float u[3], rr[3];
      #pragma unroll
      for (int e = 0; e < 3; ++e) {
        float s = 0.f, q = 0.f;
        #pragma unroll
        for (int ww = 0; ww < 4; ++ww) {
          const float2 sq = Sstats[c][((ww * 3 + e) * 4 + cb) * 16 + col];
          s += sq.x; q += sq.y;
        }
        u[e] = s * (1.f / 64.f);
        const float var = q * (1.f / 64.f) - u[e] * u[e];
        rr[e] = rsqrtf(var + LN_EPS_F);
      }
      #pragma unroll
      for (int reg = 0; reg < 4; ++reg) {
        float o = 0.f;
        #pragma unroll
        for (int e = 0; e < 3; ++e) {
          const float y = acc[cb][e][reg];
          o += ge[e] * ((&lw[e].x)[reg] * (y - u[e]) * rr[e] + (&lb[e].x)[reg]);
        }
        outb[(size_t)(co0 + reg) * NPIX + cb * 16 + col] = o;
      }
    }

    // ---- write next tile into the other buffer (compiler waits vmcnt here) ----
    if (i < TILES_PER_BLOCK - 1) {
      #pragma unroll
      for (int ii = 0; ii < 6; ++ii)
        *reinterpret_cast<uint4*>(&Bl[c ^ 1][((4 * ii + w) * 64 + lane) * 8]) = sreg[ii];
    }
  }
}

// ---------------- launch ----------------
extern "C" void kernel_launch(void* const* d_in, const int* in_sizes, int n_in,
                              void* d_out, int out_size, void* d_ws, size_t ws_size,
                              hipStream_t stream) {
  const float* x    = (const float*)d_in[0];
  const float* eW   = (const float*)d_in[1];
  const float* eB   = (const float*)d_in[2];
  const float* elnw = (const float*)d_in[3];
  const float* elnb = (const float*)d_in[4];
  const float* sW   = (const float*)d_in[5];
  const float* sB   = (const float*)d_in[6];
  const float* slnw = (const float*)d_in[7];
  const float* slnb = (const float*)d_in[8];
  const float* wg   = (const float*)d_in[9];
  float* out = (float*)d_out;

  float* loss_ptr = out + (size_t)BATCH * COUT * NPIX;  // element 6422528

  k_pre<<<N_CONV + N_GATE + N_REPACK, 256, 0, stream>>>(x, eW, sW);
  k_main<<<BATCH * TILES_PER_BLOCK, 256, 0, stream>>>(wg, eB, sB, elnw, elnb,
                                                      slnw, slnb, out, loss_ptr);
}

// Round 11
// 48.739 us; speedup vs baseline: 1.4461x; 1.1371x over previous
//
#include <hip/hip_runtime.h>
#include <cstdint>
#include <cstddef>

// ---- problem constants ----
static constexpr int BATCH = 32;
static constexpr int CIN   = 3;
static constexpr int HIN   = 224, WIN = 224;
static constexpr int COUT  = 64;
static constexpr int HOUT  = 56, WOUT = 56;
static constexpr int NPIX  = HOUT * WOUT;     // 3136 = 49*64
static constexpr int NEXP  = 8;
static constexpr int KROWS = 21;              // ci*7 + kh
static constexpr int KPAD2 = 192;             // 24 rows * 8 slots (slot0 = zero weight)
static constexpr int NKS   = 6;               // K-steps of 32
static constexpr int NGRP  = 7;               // groups per image (8 oh-rows each)
static constexpr int TPB   = 7;               // tiles per block (7 x 64 px = 448 = 8*56)
static constexpr int PWL   = 232;             // window row length (ushorts): 4 pad +224+ 4 pad
static constexpr int WR    = 35;              // window rows per ci (8*4 + 3)
static constexpr float LN_EPS_F = 1e-6f;

// k_pre role partition (gate_mean + repack only; no convert pass anymore)
static constexpr int N_GATE = BATCH * CIN;                        // 96
static constexpr int N_REPACK = (9 * COUT * KPAD2 + 255) / 256;   // 432

typedef __bf16 bf16x8 __attribute__((ext_vector_type(8)));
typedef float  f32x4  __attribute__((ext_vector_type(4)));

// ---- device-global scratch ----
__device__ __align__(16) ushort g_pw2[9 * COUT * KPAD2];  // bf16 weights, k' layout
__device__ float g_gateinp[BATCH * CIN];

__device__ __forceinline__ ushort f2bf(float f) {
  uint u = __float_as_uint(f);
  uint r = (u + 0x7FFFu + ((u >> 16) & 1u)) >> 16;        // RNE
  return (ushort)r;
}

// LDS-visibility-only barrier: drains LDS ops, leaves global stores in flight.
__device__ __forceinline__ void barrier_lgkm() {
  asm volatile("s_waitcnt lgkmcnt(0)" ::: "memory");
  __builtin_amdgcn_s_barrier();
  __builtin_amdgcn_sched_barrier(0);
}

// ---------------- kernel 1: gate_mean (0..95) / weight repack (96..527) -------
__global__ __launch_bounds__(256) void k_pre(const float* __restrict__ x,
                                             const float* __restrict__ eW,
                                             const float* __restrict__ sW) {
  const int bid = blockIdx.x;
  if (bid < N_GATE) {
    const int plane = bid;
    const float4* p4 = reinterpret_cast<const float4*>(x + (size_t)plane * (HIN * WIN));
    float s = 0.f;
    for (int i = threadIdx.x; i < (HIN * WIN) / 4; i += 256) {
      const float4 v = p4[i];
      s += v.x + v.y + v.z + v.w;
    }
    __shared__ float red[256];
    red[threadIdx.x] = s;
    __syncthreads();
    for (int off = 128; off > 0; off >>= 1) {
      if ((int)threadIdx.x < off) red[threadIdx.x] += red[threadIdx.x + off];
      __syncthreads();
    }
    if (threadIdx.x == 0) g_gateinp[plane] = red[0] * (1.f / (float)(HIN * WIN));
  } else {
    // repack -> bf16 [9][64][192]; k' = (ci*7+kh)*8 + slot; slot0 zero, slots
    // 1..7 = taps 0..6 (the +1 shift makes window B-reads 8B-aligned).
    const int idx = (bid - N_GATE) * 256 + threadIdx.x;
    if (idx >= 9 * COUT * KPAD2) return;
    const int k2  = idx % KPAD2;
    const int coe = idx / KPAD2;    // e*64 + co
    const int co  = coe & 63;
    const int e   = coe >> 6;
    const int kwp = k2 & 7;
    const int row = k2 >> 3;
    float v = 0.f;
    if (kwp >= 1 && row < KROWS) {
      const int k = row * 7 + (kwp - 1);
      v = (e < 8) ? eW[(size_t)coe * 147 + k] : sW[(size_t)co * 147 + k];
    }
    g_pw2[idx] = f2bf(v);
  }
}

// ---------------- kernel 2: windowed MFMA conv + LN + gated combine ------------
// 224 blocks x 512 threads (8 waves). Block (b,g): oh in [8g, 8g+8).
// Stage the 3x35-row f32 input window once into LDS as bf16 (48.7 KB), then
// 7 tiles with ZERO in-loop global loads; one lgkm barrier per tile.
// Wave w: wc=w>>1 -> co slice [16wc,16wc+16); wh=w&1 -> px half (cb 2wh..2wh+1).
__global__ __launch_bounds__(512, 1) void k_main(
    const float* __restrict__ x,
    const float* __restrict__ w_gate,
    const float* __restrict__ eB, const float* __restrict__ sB,
    const float* __restrict__ elnw, const float* __restrict__ elnb,
    const float* __restrict__ slnw, const float* __restrict__ slnb,
    float* __restrict__ out, float* __restrict__ loss_out) {
  __shared__ __align__(16) ushort Wnd[3 * WR * PWL];          // 48720 B
  __shared__ float2 Sstats[2][8][3][2][16];                   // 12288 B (tile parity)

  const int tid  = threadIdx.x;
  const int lane = tid & 63;
  const int w    = tid >> 6;      // 0..7
  const int b    = blockIdx.x / NGRP;
  const int g    = blockIdx.x % NGRP;

  // ---- stage window: rows ih = 32g-3 .. 32g+31 per ci, cols padded +4/+4 ----
  {
    for (int i = tid; i < 3 * WR * 28; i += 512) {
      const int j8 = i % 28;            // 8-col chunk of the input row
      const int rr = i / 28;            // ci*35 + wr
      const int ci = rr / WR;
      const int wr = rr - ci * WR;
      const int ih = 32 * g + wr - 3;
      uint2 lo = {0u, 0u}, hi = {0u, 0u};
      if ((unsigned)ih < (unsigned)HIN) {
        const float4* xr = reinterpret_cast<const float4*>(
            x + ((size_t)(b * CIN + ci) * HIN + ih) * WIN);
        const float4 f0 = xr[2 * j8];
        const float4 f1 = xr[2 * j8 + 1];
        lo.x = (uint)f2bf(f0.x) | ((uint)f2bf(f0.y) << 16);
        lo.y = (uint)f2bf(f0.z) | ((uint)f2bf(f0.w) << 16);
        hi.x = (uint)f2bf(f1.x) | ((uint)f2bf(f1.y) << 16);
        hi.y = (uint)f2bf(f1.z) | ((uint)f2bf(f1.w) << 16);
      }
      // window col = input col + 4 ; chunk starts at col 8*j8+4 (8B aligned)
      *reinterpret_cast<uint2*>(&Wnd[rr * PWL + 8 * j8 + 4]) = lo;
      *reinterpret_cast<uint2*>(&Wnd[rr * PWL + 8 * j8 + 8]) = hi;
      if (j8 == 0) {  // left pad cols 0..3
        const uint2 z = {0u, 0u};
        *reinterpret_cast<uint2*>(&Wnd[rr * PWL]) = z;
      }
      if (j8 == 27) { // right pad cols 228..231
        const uint2 z = {0u, 0u};
        *reinterpret_cast<uint2*>(&Wnd[rr * PWL + 228]) = z;
      }
    }
  }

  // ---- gating (overlaps staging latency) ----
  const float gi0 = g_gateinp[b * 3 + 0];
  const float gi1 = g_gateinp[b * 3 + 1];
  const float gi2 = g_gateinp[b * 3 + 2];
  float best1 = -1e30f, best2 = -1e30f;
  int i1 = 0, i2 = 0;
  #pragma unroll
  for (int e = 0; e < NEXP; ++e) {
    const float lg = gi0 * w_gate[e] + gi1 * w_gate[8 + e] + gi2 * w_gate[16 + e];
    if (lg > best1) { best2 = best1; i2 = i1; best1 = lg; i1 = e; }
    else if (lg > best2) { best2 = lg; i2 = e; }
  }
  const float e21 = expf(best2 - best1);
  const float g1 = 1.f / (1.f + e21);
  const float g2 = e21 / (1.f + e21);
  const int e1 = __builtin_amdgcn_readfirstlane(i1);
  const int e2 = __builtin_amdgcn_readfirstlane(i2);

  const int m    = lane >> 4;       // k-chunk 0..3
  const int colA = lane & 15;
  const int wc   = w >> 1;          // co-slice
  const int wh   = w & 1;           // px half
  const int wbase = wc * 16;
  const int eidx[3] = {e1, e2, 8};

  // ---- A-fragments once per block: 3 experts x 6 K-steps ----
  bf16x8 afrag[3][NKS];
  #pragma unroll
  for (int e = 0; e < 3; ++e) {
    const ushort* ape = g_pw2 + ((size_t)(eidx[e] * COUT + wbase + colA)) * KPAD2 + m * 8;
    #pragma unroll
    for (int ks = 0; ks < NKS; ++ks)
      afrag[e][ks] = __builtin_bit_cast(bf16x8, *reinterpret_cast<const uint4*>(ape + ks * 32));
  }

  // per-lane window row offsets per ks (k' row r = 4ks+m; r>20 clamps, wt=0)
  int Crow[NKS];
  #pragma unroll
  for (int ks = 0; ks < NKS; ++ks) {
    int r = 4 * ks + m;
    r = r > 20 ? 20 : r;
    const int ci = r >= 14 ? 2 : (r >= 7 ? 1 : 0);
    const int kh = r - ci * 7;
    Crow[ks] = (ci * WR + kh) * PWL;
  }

  // ---- block-invariant epilogue params ----
  const int co0 = wbase + m * 4;
  const int col = colA;
  float4 bias[3], lw[3], lb[3];
  bias[0] = *reinterpret_cast<const float4*>(eB + e1 * COUT + co0);
  bias[1] = *reinterpret_cast<const float4*>(eB + e2 * COUT + co0);
  bias[2] = *reinterpret_cast<const float4*>(sB + co0);
  lw[0] = *reinterpret_cast<const float4*>(elnw + e1 * COUT + co0);
  lw[1] = *reinterpret_cast<const float4*>(elnw + e2 * COUT + co0);
  lw[2] = *reinterpret_cast<const float4*>(slnw + co0);
  lb[0] = *reinterpret_cast<const float4*>(elnb + e1 * COUT + co0);
  lb[1] = *reinterpret_cast<const float4*>(elnb + e2 * COUT + co0);
  lb[2] = *reinterpret_cast<const float4*>(slnb + co0);
  const float ge[3] = {g1, g2, 1.f};

  // ---- aux loss: block 0, wave 0 ----
  if (blockIdx.x == 0 && w == 0) {
    float mg1 = 0.f, mg2 = 0.f;
    int me1 = -1, me2 = -1;
    if (lane < BATCH) {
      const float a0 = g_gateinp[lane * 3 + 0];
      const float a1 = g_gateinp[lane * 3 + 1];
      const float a2 = g_gateinp[lane * 3 + 2];
      float b1 = -1e30f, b2 = -1e30f;
      int j1 = 0, j2 = 0;
      #pragma unroll
      for (int e = 0; e < NEXP; ++e) {
        const float lg = a0 * w_gate[e] + a1 * w_gate[8 + e] + a2 * w_gate[16 + e];
        if (lg > b1) { b2 = b1; j2 = j1; b1 = lg; j1 = e; }
        else if (lg > b2) { b2 = lg; j2 = e; }
      }
      const float q = expf(b2 - b1);
      mg1 = 1.f / (1.f + q); mg2 = q / (1.f + q);
      me1 = j1; me2 = j2;
    }
    float imp[NEXP], lod[NEXP];
    #pragma unroll
    for (int e = 0; e < NEXP; ++e) {
      float ie = ((me1 == e) ? mg1 : 0.f) + ((me2 == e) ? mg2 : 0.f);
      float le = (((me1 == e) && (mg1 > 0.f)) ? 1.f : 0.f)
               + (((me2 == e) && (mg2 > 0.f)) ? 1.f : 0.f);
      #pragma unroll
      for (int o = 32; o > 0; o >>= 1) { ie += __shfl_xor(ie, o, 64); le += __shfl_xor(le, o, 64); }
      imp[e] = ie; lod[e] = le;
    }
    if (lane == 0) {
      float mi = 0.f, ml = 0.f;
      #pragma unroll
      for (int e = 0; e < NEXP; ++e) { mi += imp[e]; ml += lod[e]; }
      mi *= (1.f / NEXP); ml *= (1.f / NEXP);
      float vi = 0.f, vl = 0.f;
      #pragma unroll
      for (int e = 0; e < NEXP; ++e) {
        const float di = imp[e] - mi; vi += di * di;
        const float dl = lod[e] - ml; vl += dl * dl;
      }
      vi *= (1.f / (NEXP - 1)); vl *= (1.f / (NEXP - 1));
      loss_out[0] = 0.01f * (vi / (mi * mi + 1e-10f) + vl / (ml * ml + 1e-10f));
    }
  }

  __syncthreads();   // window visible (no pipeline to preserve here)

  float* const outb = out + (size_t)b * (COUT * NPIX);

  // ---- 7 tiles; no global loads inside; 1 lgkm barrier per tile ----
  for (int i = 0; i < TPB; ++i) {
    const int par = i & 1;
    const int t   = g * TPB + i;
    const int t64 = t * 64;

    // per-cbL window base: ((oh-8g)*4)*PWL + ow*4  (ushorts)
    int baseB[2], pxv[2];
    #pragma unroll
    for (int cbL = 0; cbL < 2; ++cbL) {
      const int px = (2 * wh + cbL) * 16 + colA;
      const int pg = t64 + px;
      const int oh = pg / WOUT;
      const int ow = pg - oh * WOUT;
      baseB[cbL] = ((oh - 8 * g) * 4) * PWL + ow * 4;
      pxv[cbL]   = px;
    }

    // ---- MFMA: acc[cbL][e] over 6 K-steps, B straight from window ----
    f32x4 acc[2][3];
    #pragma unroll
    for (int cbL = 0; cbL < 2; ++cbL)
      #pragma unroll
      for (int e = 0; e < 3; ++e) acc[cbL][e] = (f32x4){0.f, 0.f, 0.f, 0.f};

    #pragma unroll
    for (int ks = 0; ks < NKS; ++ks) {
      #pragma unroll
      for (int cbL = 0; cbL < 2; ++cbL) {
        const ushort* p = &Wnd[baseB[cbL] + Crow[ks]];
        const uint2 lo = *reinterpret_cast<const uint2*>(p);
        const uint2 hi = *reinterpret_cast<const uint2*>(p + 4);
        const uint4 raw = {lo.x, lo.y, hi.x, hi.y};
        const bf16x8 bf = __builtin_bit_cast(bf16x8, raw);
        #pragma unroll
        for (int e = 0; e < 3; ++e)
          acc[cbL][e] = __builtin_amdgcn_mfma_f32_16x16x32_bf16(afrag[e][ks], bf, acc[cbL][e], 0, 0, 0);
      }
    }

    // ---- bias + per-pixel LN stats ----
    #pragma unroll
    for (int cbL = 0; cbL < 2; ++cbL)
      #pragma unroll
      for (int e = 0; e < 3; ++e) {
        acc[cbL][e][0] += (&bias[e].x)[0];
        acc[cbL][e][1] += (&bias[e].x)[1];
        acc[cbL][e][2] += (&bias[e].x)[2];
        acc[cbL][e][3] += (&bias[e].x)[3];
      }

    #pragma unroll
    for (int cbL = 0; cbL < 2; ++cbL)
      #pragma unroll
      for (int e = 0; e < 3; ++e) {
        float s = acc[cbL][e][0] + acc[cbL][e][1] + acc[cbL][e][2] + acc[cbL][e][3];
        float q = acc[cbL][e][0] * acc[cbL][e][0] + acc[cbL][e][1] * acc[cbL][e][1]
                + acc[cbL][e][2] * acc[cbL][e][2] + acc[cbL][e][3] * acc[cbL][e][3];
        s += __shfl_xor(s, 16, 64); s += __shfl_xor(s, 32, 64);
        q += __shfl_xor(q, 16, 64); q += __shfl_xor(q, 32, 64);
        if (lane < 16) Sstats[par][w][e][cbL][col] = make_float2(s, q);
      }

    barrier_lgkm();   // stats visible; stores stay in flight

    // ---- LN + gated combine + stores (64B-segment coalesced per m-group) ----
    #pragma unroll
    for (int cbL = 0; cbL < 2; ++cbL) {
      float u[3], rr[3];
      #pragma unroll
      for (int e = 0; e < 3; ++e) {
        float s = 0.f, q = 0.f;
        #pragma unroll
        for (int wcp = 0; wcp < 4; ++wcp) {
          const float2 sq = Sstats[par][wcp * 2 + wh][e][cbL][col];
          s += sq.x; q += sq.y;
        }
        u[e] = s * (1.f / 64.f);
        const float var = q * (1.f / 64.f) - u[e] * u[e];
        rr[e] = rsqrtf(var + LN_EPS_F);
      }
      #pragma unroll
      for (int reg = 0; reg < 4; ++reg) {
        float o = 0.f;
        #pragma unroll
        for (int e = 0; e < 3; ++e) {
          const float y = acc[cbL][e][reg];
          o += ge[e] * ((&lw[e].x)[reg] * (y - u[e]) * rr[e] + (&lb[e].x)[reg]);
        }
        outb[(size_t)(co0 + reg) * NPIX + t64 + pxv[cbL]] = o;
      }
    }
  }
}

// ---------------- launch ----------------
extern "C" void kernel_launch(void* const* d_in, const int* in_sizes, int n_in,
                              void* d_out, int out_size, void* d_ws, size_t ws_size,
                              hipStream_t stream) {
  const float* x    = (const float*)d_in[0];
  const float* eW   = (const float*)d_in[1];
  const float* eB   = (const float*)d_in[2];
  const float* elnw = (const float*)d_in[3];
  const float* elnb = (const float*)d_in[4];
  const float* sW   = (const float*)d_in[5];
  const float* sB   = (const float*)d_in[6];
  const float* slnw = (const float*)d_in[7];
  const float* slnb = (const float*)d_in[8];
  const float* wg   = (const float*)d_in[9];
  float* out = (float*)d_out;

  float* loss_ptr = out + (size_t)BATCH * COUT * NPIX;  // element 6422528

  k_pre<<<N_GATE + N_REPACK, 256, 0, stream>>>(x, eW, sW);
  k_main<<<BATCH * NGRP, 512, 0, stream>>>(x, wg, eB, sB, elnw, elnb,
                                           slnw, slnb, out, loss_ptr);
}